// Round 6
// baseline (498.819 us; speedup 1.0000x reference)
//
#include <hip/hip_runtime.h>
#include <stdint.h>

// Problem constants (B=4, S=1536, D=2048, H=16, hd=128)
#define BB 4
#define SS 1536
#define DD 2048
#define HH 16
#define HD 128
#define BS (BB * SS)        // 6144 rows
#define N3 (3 * DD)         // 6144

typedef __bf16 bf16x8 __attribute__((ext_vector_type(8)));
typedef float f32x4 __attribute__((ext_vector_type(4)));

__device__ __forceinline__ void async16(const void* g, void* lds) {
  __builtin_amdgcn_global_load_lds(
      (const __attribute__((address_space(1))) unsigned int*)g,
      (__attribute__((address_space(3))) unsigned int*)lds, 16, 0, 0);
}

__global__ __launch_bounds__(256) void cast_bf16_kernel(
    const float* __restrict__ in, __bf16* __restrict__ out) {
  long i = ((long)blockIdx.x * 256 + threadIdx.x) * 8;
  float4 a = *(const float4*)(in + i);
  float4 b = *(const float4*)(in + i + 4);
  bf16x8 o;
  o[0] = (__bf16)a.x; o[1] = (__bf16)a.y; o[2] = (__bf16)a.z; o[3] = (__bf16)a.w;
  o[4] = (__bf16)b.x; o[5] = (__bf16)b.y; o[6] = (__bf16)b.z; o[7] = (__bf16)b.w;
  *(bf16x8*)(out + i) = o;
}

__global__ __launch_bounds__(256) void transpose_cast_kernel(
    const float* __restrict__ in, __bf16* __restrict__ out, int R, int C) {
  __shared__ __bf16 t[32][33];
  int tx = threadIdx.x & 31, ty = threadIdx.x >> 5;  // 32 x 8
  long r0 = (long)blockIdx.y * 32, c0 = (long)blockIdx.x * 32;
#pragma unroll
  for (int i = 0; i < 4; ++i)
    t[ty + i * 8][tx] = (__bf16)in[(r0 + ty + i * 8) * C + c0 + tx];
  __syncthreads();
#pragma unroll
  for (int i = 0; i < 4; ++i)
    out[(c0 + ty + i * 8) * R + r0 + tx] = t[tx][ty + i * 8];
}

// ---------------------------------------------------------------------------
// GEMM, m97-style structure, BK=64 (NEW this round).
// Two independently chunk-XOR-swizzled 32-k halves: sA[h][128][32], h=0,1.
// Identical staging/read/MFMA pattern per unit-K as the proven BK=32 kernel,
// but the vmcnt(0)+lgkmcnt(0) barrier drain is paid once per 32 MFMAs
// instead of 16 -> relative stall halves. LDS 32 KB/block keeps 3-4
// blocks/CU (VGPR ~120 unified -> 4 waves/SIMD), preserving the cross-block
// overlap that fills the drain stall.
// ---------------------------------------------------------------------------
__device__ __forceinline__ void store_val(__bf16* p, float v) { *p = (__bf16)v; }
__device__ __forceinline__ void store_val(float* p, float v) { *p = v; }

template <typename OutT>
__global__ __launch_bounds__(256, 2) void gemm_bt_kernel(
    const __bf16* __restrict__ A, const __bf16* __restrict__ Bt,
    const float* __restrict__ bias, OutT* __restrict__ C,
    int M, int N, int K) {
  __shared__ __attribute__((aligned(16))) __bf16 sA[2][128 * 32];  // 16 KB ea
  __shared__ __attribute__((aligned(16))) __bf16 sB[2][128 * 32];
  const int tid = threadIdx.x;
  const int wave = tid >> 6, lane = tid & 63;
  const int quad = lane >> 4, l15 = lane & 15;
  const int bm = blockIdx.y * 128, bn = blockIdx.x * 128;
  const int wr = (wave >> 1) * 64, wc = (wave & 1) * 64;

  const int srow = lane >> 2;
  const int scol = ((lane & 3) ^ ((lane >> 3) & 3)) * 8;  // swizzled source
  const __bf16* Ap = A + (long)(bm + wave * 32 + srow) * K + scol;
  const __bf16* Bp = Bt + (long)(bn + wave * 32 + srow) * K + scol;
  const int w32 = wave * 32 * 32;

  const int achunk = (quad ^ ((l15 >> 1) & 3)) * 8;  // swizzled frag read

  f32x4 acc[4][4] = {};

  for (int k0 = 0; k0 < K; k0 += 64) {
    __syncthreads();
#pragma unroll
    for (int h = 0; h < 2; ++h) {
      async16(Ap + k0 + h * 32, &sA[h][w32]);
      async16(Ap + k0 + h * 32 + (long)16 * K, &sA[h][w32 + 16 * 32]);
      async16(Bp + k0 + h * 32, &sB[h][w32]);
      async16(Bp + k0 + h * 32 + (long)16 * K, &sB[h][w32 + 16 * 32]);
    }
    __syncthreads();
#pragma unroll
    for (int h = 0; h < 2; ++h) {
      bf16x8 af[4], bfr[4];
#pragma unroll
      for (int i = 0; i < 4; ++i)
        af[i] = *(const bf16x8*)&sA[h][(wr + i * 16 + l15) * 32 + achunk];
#pragma unroll
      for (int i = 0; i < 4; ++i)
        bfr[i] = *(const bf16x8*)&sB[h][(wc + i * 16 + l15) * 32 + achunk];
#pragma unroll
      for (int i = 0; i < 4; ++i)
#pragma unroll
        for (int j = 0; j < 4; ++j)
          acc[i][j] = __builtin_amdgcn_mfma_f32_16x16x32_bf16(
              af[i], bfr[j], acc[i][j], 0, 0, 0);
    }
  }

#pragma unroll
  for (int i = 0; i < 4; ++i) {
    int row0 = bm + wr + i * 16 + quad * 4;
#pragma unroll
    for (int j = 0; j < 4; ++j) {
      int col = bn + wc + j * 16 + l15;
      float bv = bias[col];
#pragma unroll
      for (int r = 0; r < 4; ++r)
        store_val(&C[(long)(row0 + r) * N + col], acc[i][j][r] + bv);
    }
  }
}

__global__ __launch_bounds__(256) void rmsnorm_kernel(
    __bf16* __restrict__ qkv, const float* __restrict__ qw,
    const float* __restrict__ kw) {
  const int r = blockIdx.x;
  const bool isQ = r < BS;
  const int row = isQ ? r : r - BS;
  __bf16* p = qkv + (long)row * N3 + (isQ ? 0 : DD);
  const float* w = isQ ? qw : kw;
  const float extra = isQ ? (0.0883883476483184f * 1.44269504088896f) : 1.0f;
  const int t = threadIdx.x;

  bf16x8 v = *(const bf16x8*)(p + t * 8);
  float f[8];
  float s = 0.f;
#pragma unroll
  for (int i = 0; i < 8; ++i) { f[i] = (float)v[i]; s += f[i] * f[i]; }
#pragma unroll
  for (int off = 32; off > 0; off >>= 1) s += __shfl_xor(s, off, 64);
  __shared__ float red[4];
  if ((t & 63) == 0) red[t >> 6] = s;
  __syncthreads();
  float tot = red[0] + red[1] + red[2] + red[3];
  float rs = rsqrtf(tot * (1.0f / (float)DD) + 1e-6f) * extra;
  const float4 w0 = *(const float4*)(w + t * 8);
  const float4 w1 = *(const float4*)(w + t * 8 + 4);
  bf16x8 o;
  o[0] = (__bf16)(f[0] * rs * w0.x); o[1] = (__bf16)(f[1] * rs * w0.y);
  o[2] = (__bf16)(f[2] * rs * w0.z); o[3] = (__bf16)(f[3] * rs * w0.w);
  o[4] = (__bf16)(f[4] * rs * w1.x); o[5] = (__bf16)(f[5] * rs * w1.y);
  o[6] = (__bf16)(f[6] * rs * w1.z); o[7] = (__bf16)(f[7] * rs * w1.w);
  *(bf16x8*)(p + t * 8) = o;
}

__global__ __launch_bounds__(256) void transpose_v_kernel(
    const __bf16* __restrict__ qkv, __bf16* __restrict__ vt) {
  __shared__ __bf16 t[32][33];
  const int bh = blockIdx.z, b = bh >> 4, h = bh & 15;
  const int s0 = blockIdx.x * 32, d0 = blockIdx.y * 32;
  const int tx = threadIdx.x & 31, ty = threadIdx.x >> 5;
#pragma unroll
  for (int i = 0; i < 4; ++i) {
    int s = s0 + ty + i * 8;
    t[ty + i * 8][tx] =
        qkv[(long)(b * SS + s) * N3 + 2 * DD + h * HD + d0 + tx];
  }
  __syncthreads();
#pragma unroll
  for (int i = 0; i < 4; ++i) {
    int d = d0 + ty + i * 8;
    vt[((long)bh * HD + d) * SS + s0 + tx] = t[tx][ty + i * 8];
  }
}

// ---------------------------------------------------------------------------
// Flash attention v5, causal. 1-D grid of 768 blocks, LPT mapping:
//   rank r -> qi = 11 - (r>>6) (big blocks dispatch first), bh = r & 63.
// Proven round-5 version: 121 -> 71.7 us (occupancy tail fix + same-XCD
// K/V L2 locality, FETCH_SIZE 152 -> 43 MB). Unchanged this round.
// ---------------------------------------------------------------------------
__global__ __launch_bounds__(256, 2) void attn_kernel(
    const __bf16* __restrict__ qkv, const __bf16* __restrict__ vt,
    __bf16* __restrict__ O) {
  __shared__ __attribute__((aligned(16))) __bf16 sK[2][64 * 128];  // 32 KB
  __shared__ __attribute__((aligned(16))) __bf16 sV[2][128 * 64];  // 32 KB
  __shared__ __attribute__((aligned(16))) __bf16 sP[4][32 * 64];   // 16 KB

  const int rank = blockIdx.x;
  const int qi = 11 - (rank >> 6);   // LPT: big blocks first
  const int bh = rank & 63;
  const int b = bh >> 4, h = bh & 15;
  const int tid = threadIdx.x, wave = tid >> 6, lane = tid & 63;
  const int quad = lane >> 4, l15 = lane & 15;
  const int sw3 = l15 & 7;

  const long rowQ0 = (long)(b * SS + qi * 128);   // block's first q row
  const int qrow0 = qi * 128 + wave * 32;         // wave's first q row (in S)
  const __bf16* kbase = qkv + (long)(b * SS) * N3 + DD + h * HD;
  const __bf16* vbase = vt + (long)bh * HD * SS;

  // Q fragments in registers: qf[mt][kk] for row-tile mt (rows +mt*16)
  bf16x8 qf[2][4];
#pragma unroll
  for (int mt = 0; mt < 2; ++mt) {
    const __bf16* qp =
        qkv + (rowQ0 + wave * 32 + mt * 16 + l15) * N3 + h * HD + quad * 8;
#pragma unroll
    for (int kk = 0; kk < 4; ++kk) qf[mt][kk] = *(const bf16x8*)(qp + kk * 32);
  }

  f32x4 o_acc[2][8] = {};
  float l_acc[2][4] = {};

  __bf16* sPw = &sP[wave][0];
  const int jn = 2 * qi + 2;  // K tiles 0 .. 2qi+1 (block-uniform)

  // ---- staging helper (wave-uniform LDS dst bases) ----
  auto stageKV = [&](int j, int buf) {
#pragma unroll
    for (int t = 0; t < 4; ++t) {  // K tile 64x128: inst covers 4 rows
      int rbase = wave * 16 + t * 4;            // wave-uniform
      int row = rbase + quad;
      const __bf16* src =
          kbase + (long)(j * 64 + row) * N3 + ((l15 ^ (row & 7)) * 8);
      async16(src, &sK[buf][rbase * 128]);
    }
#pragma unroll
    for (int t = 0; t < 4; ++t) {  // V^T tile 128x64: inst covers 8 rows
      int rbase = wave * 32 + t * 8;            // wave-uniform
      int row = rbase + (lane >> 3);
      const __bf16* src = vbase + (long)row * SS + j * 64 +
                          (((lane & 7) ^ (row & 7)) * 8);
      async16(src, &sV[buf][rbase * 64]);
    }
  };

  stageKV(0, 0);

  for (int j = 0; j < jn; ++j) {
    const int buf = j & 1;
    __syncthreads();                 // waits stage(j) (+ prev compute done)
    if (j + 1 < jn) stageKV(j + 1, buf ^ 1);  // prefetch, hidden by compute(j)

    // wave 0/1 rows are entirely above the diagonal for the final K tile
    const bool active = !((j == 2 * qi + 1) && (wave < 2));
    if (active) {
      const bool needMask =
          ((j == 2 * qi) && (wave < 2)) || ((j == 2 * qi + 1) && (wave >= 2));

      // ---- S = Q K^T : 16 bk reads feed 32 MFMAs ----
      f32x4 sacc[2][4];
#pragma unroll
      for (int nt = 0; nt < 4; ++nt) {
        sacc[0][nt] = (f32x4){0.f, 0.f, 0.f, 0.f};
        sacc[1][nt] = (f32x4){0.f, 0.f, 0.f, 0.f};
#pragma unroll
        for (int kk = 0; kk < 4; ++kk) {
          bf16x8 bk = *(const bf16x8*)
              &sK[buf][(nt * 16 + l15) * 128 + (((kk * 4 + quad) ^ sw3) * 8)];
          sacc[0][nt] = __builtin_amdgcn_mfma_f32_16x16x32_bf16(
              qf[0][kk], bk, sacc[0][nt], 0, 0, 0);
          sacc[1][nt] = __builtin_amdgcn_mfma_f32_16x16x32_bf16(
              qf[1][kk], bk, sacc[1][nt], 0, 0, 0);
        }
      }
      if (needMask) {
#pragma unroll
        for (int mt = 0; mt < 2; ++mt) {
          int rowg0 = qrow0 + mt * 16 + quad * 4;
#pragma unroll
          for (int nt = 0; nt < 4; ++nt) {
            int colg = j * 64 + nt * 16 + l15;
#pragma unroll
            for (int r = 0; r < 4; ++r)
              if (colg > rowg0 + r) sacc[mt][nt][r] = -1e30f;
          }
        }
      }
      // ---- p = exp2(s) -> sP (wave-private), accumulate l per lane ----
#pragma unroll
      for (int mt = 0; mt < 2; ++mt) {
#pragma unroll
        for (int nt = 0; nt < 4; ++nt) {
#pragma unroll
          for (int r = 0; r < 4; ++r) {
            float pv = exp2f(sacc[mt][nt][r]);
            l_acc[mt][r] += pv;
            int prow = mt * 16 + quad * 4 + r;
            int pcol = nt * 16 + l15;
            sPw[prow * 64 + (((pcol >> 3) ^ (prow & 7)) * 8) + (pcol & 7)] =
                (__bf16)pv;
          }
        }
      }
      // ---- O += P V : 4 ap + 16 bv reads feed 32 MFMAs ----
#pragma unroll
      for (int kk = 0; kk < 2; ++kk) {
        bf16x8 ap0 = *(const bf16x8*)
            &sPw[l15 * 64 + (((kk * 4 + quad) ^ sw3) * 8)];
        bf16x8 ap1 = *(const bf16x8*)
            &sPw[(16 + l15) * 64 + (((kk * 4 + quad) ^ sw3) * 8)];
#pragma unroll
        for (int dt = 0; dt < 8; ++dt) {
          bf16x8 bv = *(const bf16x8*)
              &sV[buf][(dt * 16 + l15) * 64 + (((kk * 4 + quad) ^ sw3) * 8)];
          o_acc[0][dt] = __builtin_amdgcn_mfma_f32_16x16x32_bf16(
              ap0, bv, o_acc[0][dt], 0, 0, 0);
          o_acc[1][dt] = __builtin_amdgcn_mfma_f32_16x16x32_bf16(
              ap1, bv, o_acc[1][dt], 0, 0, 0);
        }
      }
    }
  }

  // final l reduction across the 16 lanes of each quad-row, then write O
#pragma unroll
  for (int mt = 0; mt < 2; ++mt) {
    __bf16* obase = O + (rowQ0 + wave * 32 + mt * 16 + quad * 4) * DD + h * HD;
#pragma unroll
    for (int r = 0; r < 4; ++r) {
      float l = l_acc[mt][r];
#pragma unroll
      for (int off = 1; off < 16; off <<= 1) l += __shfl_xor(l, off, 64);
      float inv = 1.0f / l;
#pragma unroll
      for (int dt = 0; dt < 8; ++dt)
        obase[(long)r * DD + dt * 16 + l15] = (__bf16)(o_acc[mt][dt][r] * inv);
    }
  }
}

extern "C" void kernel_launch(void* const* d_in, const int* in_sizes, int n_in,
                              void* d_out, int out_size, void* d_ws,
                              size_t ws_size, hipStream_t stream) {
  const float* x      = (const float*)d_in[0];
  const float* w_qkv  = (const float*)d_in[1];
  const float* b_qkv  = (const float*)d_in[2];
  const float* q_ln_w = (const float*)d_in[3];
  const float* k_ln_w = (const float*)d_in[4];
  const float* w_out  = (const float*)d_in[5];
  const float* b_out  = (const float*)d_in[6];
  float* out = (float*)d_out;

  char* w = (char*)d_ws;
  __bf16* xb    = (__bf16*)(w);
  __bf16* wqkvT = (__bf16*)(w + 25165824L);
  __bf16* woutT = (__bf16*)(w + 50331648L);
  __bf16* qkvb  = (__bf16*)(w + 58720256L);
  __bf16* vtb   = (__bf16*)(w + 134217728L);
  __bf16* atto  = xb;

  cast_bf16_kernel<<<dim3(BS * DD / 2048), 256, 0, stream>>>(x, xb);
  transpose_cast_kernel<<<dim3(N3 / 32, DD / 32), 256, 0, stream>>>(
      w_qkv, wqkvT, DD, N3);
  transpose_cast_kernel<<<dim3(DD / 32, DD / 32), 256, 0, stream>>>(
      w_out, woutT, DD, DD);

  // GEMM1 split into 3 column-chunk dispatches (each 768 blocks = 1 clean
  // round at 3 blocks/CU) so attn stays the top rocprof dispatch.
  for (int c = 0; c < 3; ++c) {
    gemm_bt_kernel<__bf16><<<dim3(DD / 128, BS / 128), 256, 0, stream>>>(
        xb, wqkvT + (long)c * DD * DD, b_qkv + c * DD, qkvb + c * DD,
        BS, N3, DD);
  }

  rmsnorm_kernel<<<dim3(2 * BS), 256, 0, stream>>>(qkvb, q_ln_w, k_ln_w);

  transpose_v_kernel<<<dim3(SS / 32, HD / 32, BB * HH), 256, 0, stream>>>(
      qkvb, vtb);

  attn_kernel<<<dim3(SS / 128 * BB * HH), 256, 0, stream>>>(qkvb, vtb, atto);

  gemm_bt_kernel<float><<<dim3(DD / 128, BS / 128), 256, 0, stream>>>(
      atto, woutT, b_out, out, BS, DD, DD);
}

// Round 7
// 480.930 us; speedup vs baseline: 1.0372x; 1.0372x over previous
//
#include <hip/hip_runtime.h>
#include <stdint.h>

// Problem constants (B=4, S=1536, D=2048, H=16, hd=128)
#define BB 4
#define SS 1536
#define DD 2048
#define HH 16
#define HD 128
#define BS (BB * SS)        // 6144 rows
#define N3 (3 * DD)         // 6144

typedef __bf16 bf16x8 __attribute__((ext_vector_type(8)));
typedef float f32x4 __attribute__((ext_vector_type(4)));

__device__ __forceinline__ void async16(const void* g, void* lds) {
  __builtin_amdgcn_global_load_lds(
      (const __attribute__((address_space(1))) unsigned int*)g,
      (__attribute__((address_space(3))) unsigned int*)lds, 16, 0, 0);
}

// ---------------------------------------------------------------------------
// Fused preamble: cast x->bf16 (blocks 0..6143), transpose+cast w_qkv
// (blocks 6144..18431), transpose+cast w_out (blocks 18432..22527).
// All three are independent BW-bound workloads; one dispatch removes two
// full-GPU drain/relaunch boundaries and lets them backfill each other.
// ---------------------------------------------------------------------------
__device__ __forceinline__ void tcast_tile(
    const float* __restrict__ in, __bf16* __restrict__ out, int R, int C,
    int bx, int by, int tid, __bf16 (&t)[32][33]) {
  int tx = tid & 31, ty = tid >> 5;  // 32 x 8
  long r0 = (long)by * 32, c0 = (long)bx * 32;
#pragma unroll
  for (int i = 0; i < 4; ++i)
    t[ty + i * 8][tx] = (__bf16)in[(r0 + ty + i * 8) * C + c0 + tx];
  __syncthreads();
#pragma unroll
  for (int i = 0; i < 4; ++i)
    out[(c0 + ty + i * 8) * R + r0 + tx] = t[tx][ty + i * 8];
}

__global__ __launch_bounds__(256) void prep_kernel(
    const float* __restrict__ x, __bf16* __restrict__ xb,
    const float* __restrict__ wq, __bf16* __restrict__ wqT,
    const float* __restrict__ wo, __bf16* __restrict__ woT) {
  __shared__ __bf16 t[32][33];
  const int r = blockIdx.x, tid = threadIdx.x;
  if (r < 6144) {                       // cast x -> bf16
    long i = ((long)r * 256 + tid) * 8;
    float4 a = *(const float4*)(x + i);
    float4 b = *(const float4*)(x + i + 4);
    bf16x8 o;
    o[0] = (__bf16)a.x; o[1] = (__bf16)a.y; o[2] = (__bf16)a.z; o[3] = (__bf16)a.w;
    o[4] = (__bf16)b.x; o[5] = (__bf16)b.y; o[6] = (__bf16)b.z; o[7] = (__bf16)b.w;
    *(bf16x8*)(xb + i) = o;
  } else if (r < 6144 + 12288) {        // w_qkv^T (R=DD rows, C=N3 cols)
    int local = r - 6144;
    tcast_tile(wq, wqT, DD, N3, local % 192, local / 192, tid, t);
  } else {                              // w_out^T
    int local = r - (6144 + 12288);
    tcast_tile(wo, woT, DD, DD, local % 64, local / 64, tid, t);
  }
}

// ---------------------------------------------------------------------------
// GEMM with XOR-swizzled LDS (chunk c of row r at slot c ^ ((r>>1)&3)).
// Round-0 proven version (BK=32): 761 TF, no spills, 0 bank conflicts.
// BK=64 variant (round 6) was neutral-to-negative -> reverted.
// GEMM1 runs as 3 column-chunk dispatches (768 blocks each, 1 clean round
// at 3 blocks/CU) to keep attn visible as the top rocprof dispatch.
// ---------------------------------------------------------------------------
__device__ __forceinline__ void store_val(__bf16* p, float v) { *p = (__bf16)v; }
__device__ __forceinline__ void store_val(float* p, float v) { *p = v; }

template <typename OutT>
__global__ __launch_bounds__(256, 2) void gemm_bt_kernel(
    const __bf16* __restrict__ A, const __bf16* __restrict__ Bt,
    const float* __restrict__ bias, OutT* __restrict__ C,
    int M, int N, int K) {
  __shared__ __attribute__((aligned(16))) __bf16 sA[128 * 32];
  __shared__ __attribute__((aligned(16))) __bf16 sB[128 * 32];
  const int tid = threadIdx.x;
  const int wave = tid >> 6, lane = tid & 63;
  const int quad = lane >> 4, l15 = lane & 15;
  const int bm = blockIdx.y * 128, bn = blockIdx.x * 128;
  const int wr = (wave >> 1) * 64, wc = (wave & 1) * 64;

  const int srow = lane >> 2;
  const int scol = ((lane & 3) ^ ((lane >> 3) & 3)) * 8;  // swizzled source
  const __bf16* Ap = A + (long)(bm + wave * 32 + srow) * K + scol;
  const __bf16* Bp = Bt + (long)(bn + wave * 32 + srow) * K + scol;
  __bf16* sAw = &sA[wave * 32 * 32];
  __bf16* sBw = &sB[wave * 32 * 32];

  const int achunk = (quad ^ ((l15 >> 1) & 3)) * 8;  // swizzled frag read

  f32x4 acc[4][4] = {};

  for (int k0 = 0; k0 < K; k0 += 32) {
    __syncthreads();
    async16(Ap + k0, sAw);
    async16(Ap + k0 + (long)16 * K, sAw + 16 * 32);
    async16(Bp + k0, sBw);
    async16(Bp + k0 + (long)16 * K, sBw + 16 * 32);
    __syncthreads();
    bf16x8 af[4], bfr[4];
#pragma unroll
    for (int i = 0; i < 4; ++i)
      af[i] = *(const bf16x8*)&sA[(wr + i * 16 + l15) * 32 + achunk];
#pragma unroll
    for (int i = 0; i < 4; ++i)
      bfr[i] = *(const bf16x8*)&sB[(wc + i * 16 + l15) * 32 + achunk];
#pragma unroll
    for (int i = 0; i < 4; ++i)
#pragma unroll
      for (int j = 0; j < 4; ++j)
        acc[i][j] = __builtin_amdgcn_mfma_f32_16x16x32_bf16(af[i], bfr[j],
                                                            acc[i][j], 0, 0, 0);
  }

#pragma unroll
  for (int i = 0; i < 4; ++i) {
    int row0 = bm + wr + i * 16 + quad * 4;
#pragma unroll
    for (int j = 0; j < 4; ++j) {
      int col = bn + wc + j * 16 + l15;
      float bv = bias[col];
#pragma unroll
      for (int r = 0; r < 4; ++r)
        store_val(&C[(long)(row0 + r) * N + col], acc[i][j][r] + bv);
    }
  }
}

// ---------------------------------------------------------------------------
// Fused post-GEMM1: rmsnorm over Q,K rows (blocks 0..12287) + V transpose
// (blocks 12288..24575). The two touch disjoint column ranges of qkvb and
// are fully independent; fusing removes one dispatch boundary.
// ---------------------------------------------------------------------------
__global__ __launch_bounds__(256) void norm_vt_kernel(
    __bf16* __restrict__ qkv, const float* __restrict__ qw,
    const float* __restrict__ kw, __bf16* __restrict__ vt) {
  __shared__ float red[4];
  __shared__ __bf16 t[32][33];
  const int blk = blockIdx.x, tid = threadIdx.x;

  if (blk < 2 * BS) {  // ---- rmsnorm on row blk ----
    const int r = blk;
    const bool isQ = r < BS;
    const int row = isQ ? r : r - BS;
    __bf16* p = qkv + (long)row * N3 + (isQ ? 0 : DD);
    const float* w = isQ ? qw : kw;
    const float extra = isQ ? (0.0883883476483184f * 1.44269504088896f) : 1.0f;

    bf16x8 v = *(const bf16x8*)(p + tid * 8);
    float f[8];
    float s = 0.f;
#pragma unroll
    for (int i = 0; i < 8; ++i) { f[i] = (float)v[i]; s += f[i] * f[i]; }
#pragma unroll
    for (int off = 32; off > 0; off >>= 1) s += __shfl_xor(s, off, 64);
    if ((tid & 63) == 0) red[tid >> 6] = s;
    __syncthreads();
    float tot = red[0] + red[1] + red[2] + red[3];
    float rs = rsqrtf(tot * (1.0f / (float)DD) + 1e-6f) * extra;
    const float4 w0 = *(const float4*)(w + tid * 8);
    const float4 w1 = *(const float4*)(w + tid * 8 + 4);
    bf16x8 o;
    o[0] = (__bf16)(f[0] * rs * w0.x); o[1] = (__bf16)(f[1] * rs * w0.y);
    o[2] = (__bf16)(f[2] * rs * w0.z); o[3] = (__bf16)(f[3] * rs * w0.w);
    o[4] = (__bf16)(f[4] * rs * w1.x); o[5] = (__bf16)(f[5] * rs * w1.y);
    o[6] = (__bf16)(f[6] * rs * w1.z); o[7] = (__bf16)(f[7] * rs * w1.w);
    *(bf16x8*)(p + tid * 8) = o;
  } else {  // ---- transpose V tile ----
    int local = blk - 2 * BS;               // orig grid (48, 4, 64), x fastest
    const int bh = local / 192;
    const int rem = local % 192;
    const int d0 = (rem / 48) * 32;
    const int s0 = (rem % 48) * 32;
    const int b = bh >> 4, h = bh & 15;
    const int tx = tid & 31, ty = tid >> 5;
#pragma unroll
    for (int i = 0; i < 4; ++i) {
      int s = s0 + ty + i * 8;
      t[ty + i * 8][tx] =
          qkv[(long)(b * SS + s) * N3 + 2 * DD + h * HD + d0 + tx];
    }
    __syncthreads();
#pragma unroll
    for (int i = 0; i < 4; ++i) {
      int d = d0 + ty + i * 8;
      vt[((long)bh * HD + d) * SS + s0 + tx] = t[tx][ty + i * 8];
    }
  }
}

// ---------------------------------------------------------------------------
// Flash attention v5, causal. 1-D grid of 768 blocks, LPT mapping:
//   rank r -> qi = 11 - (r>>6) (big blocks dispatch first), bh = r & 63.
// Proven round-5 version: 121 -> 71.7 us (occupancy tail fix + same-XCD
// K/V L2 locality, FETCH_SIZE 152 -> 43 MB). Unchanged this round.
// ---------------------------------------------------------------------------
__global__ __launch_bounds__(256, 2) void attn_kernel(
    const __bf16* __restrict__ qkv, const __bf16* __restrict__ vt,
    __bf16* __restrict__ O) {
  __shared__ __attribute__((aligned(16))) __bf16 sK[2][64 * 128];  // 32 KB
  __shared__ __attribute__((aligned(16))) __bf16 sV[2][128 * 64];  // 32 KB
  __shared__ __attribute__((aligned(16))) __bf16 sP[4][32 * 64];   // 16 KB

  const int rank = blockIdx.x;
  const int qi = 11 - (rank >> 6);   // LPT: big blocks first
  const int bh = rank & 63;
  const int b = bh >> 4, h = bh & 15;
  const int tid = threadIdx.x, wave = tid >> 6, lane = tid & 63;
  const int quad = lane >> 4, l15 = lane & 15;
  const int sw3 = l15 & 7;

  const long rowQ0 = (long)(b * SS + qi * 128);   // block's first q row
  const int qrow0 = qi * 128 + wave * 32;         // wave's first q row (in S)
  const __bf16* kbase = qkv + (long)(b * SS) * N3 + DD + h * HD;
  const __bf16* vbase = vt + (long)bh * HD * SS;

  // Q fragments in registers: qf[mt][kk] for row-tile mt (rows +mt*16)
  bf16x8 qf[2][4];
#pragma unroll
  for (int mt = 0; mt < 2; ++mt) {
    const __bf16* qp =
        qkv + (rowQ0 + wave * 32 + mt * 16 + l15) * N3 + h * HD + quad * 8;
#pragma unroll
    for (int kk = 0; kk < 4; ++kk) qf[mt][kk] = *(const bf16x8*)(qp + kk * 32);
  }

  f32x4 o_acc[2][8] = {};
  float l_acc[2][4] = {};

  __bf16* sPw = &sP[wave][0];
  const int jn = 2 * qi + 2;  // K tiles 0 .. 2qi+1 (block-uniform)

  // ---- staging helper (wave-uniform LDS dst bases) ----
  auto stageKV = [&](int j, int buf) {
#pragma unroll
    for (int t = 0; t < 4; ++t) {  // K tile 64x128: inst covers 4 rows
      int rbase = wave * 16 + t * 4;            // wave-uniform
      int row = rbase + quad;
      const __bf16* src =
          kbase + (long)(j * 64 + row) * N3 + ((l15 ^ (row & 7)) * 8);
      async16(src, &sK[buf][rbase * 128]);
    }
#pragma unroll
    for (int t = 0; t < 4; ++t) {  // V^T tile 128x64: inst covers 8 rows
      int rbase = wave * 32 + t * 8;            // wave-uniform
      int row = rbase + (lane >> 3);
      const __bf16* src = vbase + (long)row * SS + j * 64 +
                          (((lane & 7) ^ (row & 7)) * 8);
      async16(src, &sV[buf][rbase * 64]);
    }
  };

  stageKV(0, 0);

  for (int j = 0; j < jn; ++j) {
    const int buf = j & 1;
    __syncthreads();                 // waits stage(j) (+ prev compute done)
    if (j + 1 < jn) stageKV(j + 1, buf ^ 1);  // prefetch, hidden by compute(j)

    // wave 0/1 rows are entirely above the diagonal for the final K tile
    const bool active = !((j == 2 * qi + 1) && (wave < 2));
    if (active) {
      const bool needMask =
          ((j == 2 * qi) && (wave < 2)) || ((j == 2 * qi + 1) && (wave >= 2));

      // ---- S = Q K^T : 16 bk reads feed 32 MFMAs ----
      f32x4 sacc[2][4];
#pragma unroll
      for (int nt = 0; nt < 4; ++nt) {
        sacc[0][nt] = (f32x4){0.f, 0.f, 0.f, 0.f};
        sacc[1][nt] = (f32x4){0.f, 0.f, 0.f, 0.f};
#pragma unroll
        for (int kk = 0; kk < 4; ++kk) {
          bf16x8 bk = *(const bf16x8*)
              &sK[buf][(nt * 16 + l15) * 128 + (((kk * 4 + quad) ^ sw3) * 8)];
          sacc[0][nt] = __builtin_amdgcn_mfma_f32_16x16x32_bf16(
              qf[0][kk], bk, sacc[0][nt], 0, 0, 0);
          sacc[1][nt] = __builtin_amdgcn_mfma_f32_16x16x32_bf16(
              qf[1][kk], bk, sacc[1][nt], 0, 0, 0);
        }
      }
      if (needMask) {
#pragma unroll
        for (int mt = 0; mt < 2; ++mt) {
          int rowg0 = qrow0 + mt * 16 + quad * 4;
#pragma unroll
          for (int nt = 0; nt < 4; ++nt) {
            int colg = j * 64 + nt * 16 + l15;
#pragma unroll
            for (int r = 0; r < 4; ++r)
              if (colg > rowg0 + r) sacc[mt][nt][r] = -1e30f;
          }
        }
      }
      // ---- p = exp2(s) -> sP (wave-private), accumulate l per lane ----
#pragma unroll
      for (int mt = 0; mt < 2; ++mt) {
#pragma unroll
        for (int nt = 0; nt < 4; ++nt) {
#pragma unroll
          for (int r = 0; r < 4; ++r) {
            float pv = exp2f(sacc[mt][nt][r]);
            l_acc[mt][r] += pv;
            int prow = mt * 16 + quad * 4 + r;
            int pcol = nt * 16 + l15;
            sPw[prow * 64 + (((pcol >> 3) ^ (prow & 7)) * 8) + (pcol & 7)] =
                (__bf16)pv;
          }
        }
      }
      // ---- O += P V : 4 ap + 16 bv reads feed 32 MFMAs ----
#pragma unroll
      for (int kk = 0; kk < 2; ++kk) {
        bf16x8 ap0 = *(const bf16x8*)
            &sPw[l15 * 64 + (((kk * 4 + quad) ^ sw3) * 8)];
        bf16x8 ap1 = *(const bf16x8*)
            &sPw[(16 + l15) * 64 + (((kk * 4 + quad) ^ sw3) * 8)];
#pragma unroll
        for (int dt = 0; dt < 8; ++dt) {
          bf16x8 bv = *(const bf16x8*)
              &sV[buf][(dt * 16 + l15) * 64 + (((kk * 4 + quad) ^ sw3) * 8)];
          o_acc[0][dt] = __builtin_amdgcn_mfma_f32_16x16x32_bf16(
              ap0, bv, o_acc[0][dt], 0, 0, 0);
          o_acc[1][dt] = __builtin_amdgcn_mfma_f32_16x16x32_bf16(
              ap1, bv, o_acc[1][dt], 0, 0, 0);
        }
      }
    }
  }

  // final l reduction across the 16 lanes of each quad-row, then write O
#pragma unroll
  for (int mt = 0; mt < 2; ++mt) {
    __bf16* obase = O + (rowQ0 + wave * 32 + mt * 16 + quad * 4) * DD + h * HD;
#pragma unroll
    for (int r = 0; r < 4; ++r) {
      float l = l_acc[mt][r];
#pragma unroll
      for (int off = 1; off < 16; off <<= 1) l += __shfl_xor(l, off, 64);
      float inv = 1.0f / l;
#pragma unroll
      for (int dt = 0; dt < 8; ++dt)
        obase[(long)r * DD + dt * 16 + l15] = (__bf16)(o_acc[mt][dt][r] * inv);
    }
  }
}

extern "C" void kernel_launch(void* const* d_in, const int* in_sizes, int n_in,
                              void* d_out, int out_size, void* d_ws,
                              size_t ws_size, hipStream_t stream) {
  const float* x      = (const float*)d_in[0];
  const float* w_qkv  = (const float*)d_in[1];
  const float* b_qkv  = (const float*)d_in[2];
  const float* q_ln_w = (const float*)d_in[3];
  const float* k_ln_w = (const float*)d_in[4];
  const float* w_out  = (const float*)d_in[5];
  const float* b_out  = (const float*)d_in[6];
  float* out = (float*)d_out;

  char* w = (char*)d_ws;
  __bf16* xb    = (__bf16*)(w);
  __bf16* wqkvT = (__bf16*)(w + 25165824L);
  __bf16* woutT = (__bf16*)(w + 50331648L);
  __bf16* qkvb  = (__bf16*)(w + 58720256L);
  __bf16* vtb   = (__bf16*)(w + 134217728L);
  __bf16* atto  = xb;

  // Fused preamble: cast + both weight transposes in one dispatch.
  prep_kernel<<<dim3(6144 + 12288 + 4096), 256, 0, stream>>>(
      x, xb, w_qkv, wqkvT, w_out, woutT);

  // GEMM1 split into 3 column-chunk dispatches (each 768 blocks = 1 clean
  // round at 3 blocks/CU) so attn stays the top rocprof dispatch.
  for (int c = 0; c < 3; ++c) {
    gemm_bt_kernel<__bf16><<<dim3(DD / 128, BS / 128), 256, 0, stream>>>(
        xb, wqkvT + (long)c * DD * DD, b_qkv + c * DD, qkvb + c * DD,
        BS, N3, DD);
  }

  // Fused rmsnorm (Q,K) + V transpose in one dispatch.
  norm_vt_kernel<<<dim3(2 * BS + 12288), 256, 0, stream>>>(
      qkvb, q_ln_w, k_ln_w, vtb);

  attn_kernel<<<dim3(SS / 128 * BB * HH), 256, 0, stream>>>(qkvb, vtb, atto);

  gemm_bt_kernel<float><<<dim3(DD / 128, BS / 128), 256, 0, stream>>>(
      atto, woutT, b_out, out, BS, DD, DD);
}